// Round 5
// baseline (35.355 us; speedup 1.0000x reference)
//
#include <hip/hip_runtime.h>

// LIF constant-current encoder: events[t, e] = spike of neuron e at step t.
// v' = v + 0.1*((0 - v) + i); i' = i + 0.2*(-i); z = (v' - 1 > 0);
// v <- z ? 0 : v'; i <- i' + x.
// All arithmetic via explicitly-rounded intrinsics to match numpy f32
// mul-then-add exactly (no FMA contraction; spikes are 0/1, absmax thr 2e-2).
// R3: nontemporal stores REGRESSED (27.8->34.5us) — reverted.
// R4: 2x grid time-split occupancy boost NEUTRAL (28.7us) — reverted.
// R5: back to R1 structure + compile-time STEPS=32 specialization so the
// t-loop fully unrolls (batched address math, deeper store clustering).

template <int STEPS>
__global__ __launch_bounds__(256) void lif_encode_kernel(
    const float4* __restrict__ in4, float* __restrict__ out, int n4) {
  const int gid = blockIdx.x * 256 + threadIdx.x;
  if (gid >= n4) return;

  const float4 xin = in4[gid];
  float x[4] = {xin.x, xin.y, xin.z, xin.w};
  float v[4] = {0.0f, 0.0f, 0.0f, 0.0f};
  float c[4] = {0.0f, 0.0f, 0.0f, 0.0f};

  float4* out4 = reinterpret_cast<float4*>(out);

#pragma unroll
  for (int t = 0; t < STEPS; ++t) {
    float z[4];
#pragma unroll
    for (int j = 0; j < 4; ++j) {
      // v_decayed = v + 0.1f * ((0 - v) + i)   [numpy f32 order, no FMA]
      float tmp = __fadd_rn(__fsub_rn(0.0f, v[j]), c[j]);
      float vd  = __fadd_rn(v[j], __fmul_rn(0.1f, tmp));
      // i_decayed = i + 0.2f * (-i)
      float id  = __fadd_rn(c[j], __fmul_rn(0.2f, __fsub_rn(0.0f, c[j])));
      // z = (v_decayed - 1.0f > 0)
      bool spike = (__fsub_rn(vd, 1.0f) > 0.0f);
      z[j] = spike ? 1.0f : 0.0f;
      v[j] = spike ? 0.0f : vd;
      c[j] = __fadd_rn(id, x[j]);
    }
    out4[(size_t)t * n4 + gid] = make_float4(z[0], z[1], z[2], z[3]);
  }
}

// Runtime-steps fallback (identical math) in case steps != 32.
__global__ __launch_bounds__(256) void lif_encode_kernel_rt(
    const float4* __restrict__ in4, float* __restrict__ out, int n4,
    int steps) {
  const int gid = blockIdx.x * 256 + threadIdx.x;
  if (gid >= n4) return;
  const float4 xin = in4[gid];
  float x[4] = {xin.x, xin.y, xin.z, xin.w};
  float v[4] = {0.0f, 0.0f, 0.0f, 0.0f};
  float c[4] = {0.0f, 0.0f, 0.0f, 0.0f};
  float4* out4 = reinterpret_cast<float4*>(out);
  for (int t = 0; t < steps; ++t) {
    float z[4];
#pragma unroll
    for (int j = 0; j < 4; ++j) {
      float tmp = __fadd_rn(__fsub_rn(0.0f, v[j]), c[j]);
      float vd  = __fadd_rn(v[j], __fmul_rn(0.1f, tmp));
      float id  = __fadd_rn(c[j], __fmul_rn(0.2f, __fsub_rn(0.0f, c[j])));
      bool spike = (__fsub_rn(vd, 1.0f) > 0.0f);
      z[j] = spike ? 1.0f : 0.0f;
      v[j] = spike ? 0.0f : vd;
      c[j] = __fadd_rn(id, x[j]);
    }
    out4[(size_t)t * n4 + gid] = make_float4(z[0], z[1], z[2], z[3]);
  }
}

extern "C" void kernel_launch(void* const* d_in, const int* in_sizes, int n_in,
                              void* d_out, int out_size, void* d_ws, size_t ws_size,
                              hipStream_t stream) {
  const float* in = (const float*)d_in[0];
  float* out = (float*)d_out;
  const int n = in_sizes[0];          // 3*640*640 = 1228800 (divisible by 4)
  const int steps = out_size / n;     // 32
  const int n4 = n >> 2;
  const int block = 256;
  const int grid = (n4 + block - 1) / block;  // 1200 blocks
  if (steps == 32) {
    lif_encode_kernel<32><<<grid, block, 0, stream>>>(
        (const float4*)in, out, n4);
  } else {
    lif_encode_kernel_rt<<<grid, block, 0, stream>>>(
        (const float4*)in, out, n4, steps);
  }
}

// Round 6
// 27.832 us; speedup vs baseline: 1.2703x; 1.2703x over previous
//
#include <hip/hip_runtime.h>

// LIF constant-current encoder: events[t, e] = spike of neuron e at step t.
// v' = v + 0.1*((0 - v) + i); i' = i + 0.2*(-i); z = (v' - 1 > 0);
// v <- z ? 0 : v'; i <- i' + x.
// All arithmetic via explicitly-rounded intrinsics to match numpy f32
// mul-then-add exactly (no FMA contraction; spikes are 0/1, absmax thr 2e-2).
//
// FINAL (R6 = R1 restored): runtime t-loop, 4 elems/thread, 1200 blocks.
// Falsified alternatives — do not retry:
//   R3 nontemporal stores: 27.8 -> 34.5 us (nt bypass loses L2 coalescing)
//   R4 2x grid time-split: 28.7 us (occupancy not the limiter)
//   R5 full unroll STEPS=32: 35.4 us (store clustering over-saturates queue)
// Roofline: 157.3 MB mandated f32 write @ ~6.9 TB/s (memset-calibrated)
// = 22.8 us + ~1 us read + ~3-4 us launch overhead ~= 27 us floor;
// R1 measured 27.8 us => within ~3%.

__global__ __launch_bounds__(256) void CurrentEncode_57286273794981_kernel(
    const float4* __restrict__ in4, float* __restrict__ out,
    int n, int steps) {
  const int gid = blockIdx.x * 256 + threadIdx.x;
  const int n4 = n >> 2;
  if (gid >= n4) return;

  const float4 xin = in4[gid];
  float x[4] = {xin.x, xin.y, xin.z, xin.w};
  float v[4] = {0.0f, 0.0f, 0.0f, 0.0f};
  float c[4] = {0.0f, 0.0f, 0.0f, 0.0f};

  float4* out4 = reinterpret_cast<float4*>(out);
  const int n4row = n4;  // float4s per time-step row

  for (int t = 0; t < steps; ++t) {
    float z[4];
#pragma unroll
    for (int j = 0; j < 4; ++j) {
      // v_decayed = v + 0.1f * ((0 - v) + i)   [numpy f32 order, no FMA]
      float tmp = __fadd_rn(__fsub_rn(0.0f, v[j]), c[j]);
      float vd  = __fadd_rn(v[j], __fmul_rn(0.1f, tmp));
      // i_decayed = i + 0.2f * (-i)
      float id  = __fadd_rn(c[j], __fmul_rn(0.2f, __fsub_rn(0.0f, c[j])));
      // z = (v_decayed - 1.0f > 0)
      bool spike = (__fsub_rn(vd, 1.0f) > 0.0f);
      z[j] = spike ? 1.0f : 0.0f;
      // v_new = z ? V_RESET : v_decayed  (exact: (1-z)*vd + z*0)
      v[j] = spike ? 0.0f : vd;
      // i_new = i_decayed + x
      c[j] = __fadd_rn(id, x[j]);
    }
    out4[(size_t)t * n4row + gid] = make_float4(z[0], z[1], z[2], z[3]);
  }
}

extern "C" void kernel_launch(void* const* d_in, const int* in_sizes, int n_in,
                              void* d_out, int out_size, void* d_ws, size_t ws_size,
                              hipStream_t stream) {
  const float* in = (const float*)d_in[0];
  float* out = (float*)d_out;
  const int n = in_sizes[0];          // 3*640*640 = 1228800 (divisible by 4)
  const int steps = out_size / n;     // 32
  const int n4 = n >> 2;
  const int block = 256;
  const int grid = (n4 + block - 1) / block;  // 1200 blocks
  CurrentEncode_57286273794981_kernel<<<grid, block, 0, stream>>>(
      (const float4*)in, out, n, steps);
}